// Round 16
// baseline (179.079 us; speedup 1.0000x reference)
//
#include <hip/hip_runtime.h>
#include <hip/hip_bf16.h>

// Attention B=4,N=2048,D=384,H=8,DH=48 — Round 15:
//  - attn: key-split ACROSS blocks (grid 32x16x2, halves of K) -> 4 blk/CU,
//    16 waves/CU. Per-block pattern identical to R13; partials (O^T + l, fp32)
//    summed+normalized by a small finalize kernel (no-max softmax => additive).
//  - prep / qkv (R14 128x128) / proj unchanged.

typedef _Float16 f16x8 __attribute__((ext_vector_type(8)));
typedef _Float16 f16x4 __attribute__((ext_vector_type(4)));
typedef float    f32x4 __attribute__((ext_vector_type(4)));
typedef float    f32x16 __attribute__((ext_vector_type(16)));

// scale * log2(e) = 48^-0.5 * 1.4426950408889634
#define QSCL 0.20822035963448658f

#define OPSTRIDE 52              // fp32 cols per partial row (48 d + l @48, pad)
#define OPTILE   (128 * OPSTRIDE) // floats per (bh,qt) tile
#define OPHALF   ((size_t)512 * OPTILE)

// ---------------------------------------------------------------------------
// prep: blocks 0..143 transpose weights (LDS-tiled); 144..399 convert x->f16
// ---------------------------------------------------------------------------
__global__ __launch_bounds__(256) void prep(const float4* __restrict__ x,
                                            const float* __restrict__ wq,
                                            const float* __restrict__ wp,
                                            f16x4* __restrict__ xh4,
                                            _Float16* __restrict__ wqt,
                                            _Float16* __restrict__ wpt)
{
    __shared__ _Float16 t[64][65];
    const int blk = blockIdx.x, tid = threadIdx.x;
    if (blk < 144) {
        const float* src; _Float16* dst; int Nn, k0, n0;
        if (blk < 108) {            // Wqkv: 6 k-tiles x 18 n-tiles
            src = wq; dst = wqt; Nn = 1152;
            k0 = (blk % 6) * 64; n0 = (blk / 6) * 64;
        } else {                    // Wproj: 6 x 6
            const int b2 = blk - 108;
            src = wp; dst = wpt; Nn = 384;
            k0 = (b2 % 6) * 64; n0 = (b2 / 6) * 64;
        }
        #pragma unroll
        for (int i = 0; i < 16; i++) {
            const int id = tid + i * 256;
            const int k = id >> 6, n = id & 63;      // coalesced over n
            t[k][n] = (_Float16)src[(size_t)(k0 + k) * Nn + n0 + n];
        }
        __syncthreads();
        #pragma unroll
        for (int i = 0; i < 16; i++) {
            const int id = tid + i * 256;
            const int n = id >> 6, k = id & 63;      // coalesced over k
            dst[(size_t)(n0 + n) * 384 + k0 + k] = t[k][n];
        }
    } else {
        const int base = (blk - 144) * 3072;         // 256 blocks x 3072 = 786432
        #pragma unroll
        for (int r = 0; r < 12; r++) {
            const int j = base + r * 256 + tid;
            const float4 tt = x[j];
            f16x4 hh;
            hh[0] = (_Float16)tt.x; hh[1] = (_Float16)tt.y;
            hh[2] = (_Float16)tt.z; hh[3] = (_Float16)tt.w;
            xh4[j] = hh;
        }
    }
}

// ---------------------------------------------------------------------------
// QKV GEMM (R14): A = xh[8192][384] f16, Bt = wqkvt[1152][384] f16.
// 128x128 tile, BK=32, 16x16x32 MFMA, 4 waves, reg-prefetch; LDS-transpose
// epilogues for q/k (scaled) and V (transposed).
// ---------------------------------------------------------------------------
union QkvSmem {
    struct { _Float16 As[128][40]; _Float16 Bs[128][40]; } g;  // 20480 B
    _Float16 Ts[128][136];   // V transpose   [col][n]   34816 B
    _Float16 Ts2[128][136];  // q/k transpose [row][col] 34816 B
};

__global__ __launch_bounds__(256) void qkv_f16(const _Float16* __restrict__ A,
                                               const _Float16* __restrict__ Bt,
                                               _Float16* __restrict__ qh,
                                               _Float16* __restrict__ kh,
                                               _Float16* __restrict__ vt)
{
    __shared__ QkvSmem sm;
    const int tid = threadIdx.x;
    const int w = tid >> 6, lane = tid & 63, cl = lane & 15, quad = lane >> 4;
    const int bm = blockIdx.x, bn = blockIdx.y;

    f32x4 acc[2][8];
    const f32x4 z4 = {0.f, 0.f, 0.f, 0.f};
    #pragma unroll
    for (int mi = 0; mi < 2; mi++)
        #pragma unroll
        for (int t = 0; t < 8; t++) acc[mi][t] = z4;

    const int ar = tid >> 2, ac = (tid & 3) * 8;
    const _Float16* Ag = A  + (size_t)(bm * 128 + ar) * 384 + ac;
    const _Float16* Bg = Bt + (size_t)(bn * 128 + ar) * 384 + ac;

    f16x8 pa[2], pb[2];
    #pragma unroll
    for (int j = 0; j < 2; j++) {
        pa[j] = *(const f16x8*)(Ag + (size_t)(64 * j) * 384);
        pb[j] = *(const f16x8*)(Bg + (size_t)(64 * j) * 384);
    }

    for (int k0 = 0; k0 < 384; k0 += 32) {
        __syncthreads();
        #pragma unroll
        for (int j = 0; j < 2; j++) {
            *(f16x8*)&sm.g.As[ar + 64 * j][ac] = pa[j];
            *(f16x8*)&sm.g.Bs[ar + 64 * j][ac] = pb[j];
        }
        __syncthreads();
        if (k0 + 32 < 384) {
            #pragma unroll
            for (int j = 0; j < 2; j++) {
                pa[j] = *(const f16x8*)(Ag + (size_t)(64 * j) * 384 + k0 + 32);
                pb[j] = *(const f16x8*)(Bg + (size_t)(64 * j) * 384 + k0 + 32);
            }
        }
        f16x8 bf[8];
        #pragma unroll
        for (int t = 0; t < 8; t++)
            bf[t] = *(const f16x8*)&sm.g.Bs[t * 16 + cl][quad * 8];
        #pragma unroll
        for (int mi = 0; mi < 2; mi++) {
            const f16x8 af = *(const f16x8*)&sm.g.As[w * 32 + mi * 16 + cl][quad * 8];
            #pragma unroll
            for (int t = 0; t < 8; t++)
                acc[mi][t] = __builtin_amdgcn_mfma_f32_16x16x32_f16(af, bf[t], acc[mi][t], 0, 0, 0);
        }
    }

    const int s = (bn * 128) / 384;
    const int b  = (bm * 128) >> 11;
    const int n0 = (bm * 128) & 2047;
    if (s == 2) {
        __syncthreads();
        #pragma unroll
        for (int t = 0; t < 8; t++)
            #pragma unroll
            for (int mi = 0; mi < 2; mi++)
                #pragma unroll
                for (int r = 0; r < 4; r++)
                    sm.Ts[t * 16 + cl][w * 32 + mi * 16 + quad * 4 + r] =
                        (_Float16)acc[mi][t][r];
        __syncthreads();
        const int colbase = bn * 128 - 768;
        #pragma unroll
        for (int i = 0; i < 8; i++) {
            const int c = i * 256 + tid;
            const int col = c >> 4, nc = c & 15;
            const int gcol = colbase + col;
            const int head = gcol / 48, d = gcol - head * 48;
            const int bh = b * 8 + head;
            *(f16x8*)&vt[(size_t)(bh * 48 + d) * 2048 + n0 + nc * 8] =
                *(const f16x8*)&sm.Ts[col][nc * 8];
        }
    } else {
        __syncthreads();
        const float scl = (s == 0) ? QSCL : 1.0f;
        #pragma unroll
        for (int t = 0; t < 8; t++)
            #pragma unroll
            for (int mi = 0; mi < 2; mi++)
                #pragma unroll
                for (int r = 0; r < 4; r++)
                    sm.Ts2[w * 32 + mi * 16 + quad * 4 + r][t * 16 + cl] =
                        (_Float16)(acc[mi][t][r] * scl);
        __syncthreads();
        _Float16* dst = (s == 0) ? qh : kh;
        const int colbase = bn * 128 - s * 384;
        #pragma unroll
        for (int i = 0; i < 8; i++) {
            const int c = i * 256 + tid;
            const int row = c >> 4, ch = c & 15;
            const int gcol = colbase + ch * 8;
            const int head = gcol / 48, d = gcol - head * 48;
            const int bh = b * 8 + head;
            *(f16x8*)&dst[(size_t)(bh * 2048 + n0 + row) * 48 + d] =
                *(const f16x8*)&sm.Ts2[row][ch * 8];
        }
    }
}

// ---------------------------------------------------------------------------
// Flash attention (R13 structure), key-split across blocks (blockIdx.z=half).
// Each block: 16 key-tiles, register-P via kappa permutation, l via ones-row.
// Partial epilogue: O^T -> LDS transpose (fp32) -> [q][52] fp32 rows + l@48.
// ---------------------------------------------------------------------------
union AttnSmem {
    struct {
        _Float16 Ks[64][56];    // [key][dh]        7168 B
        _Float16 Vts[64][72];   // [dh][key-slot]   9216 B; row 48 ones, 49-63 zero
    } a;
    float Otf[128][OPSTRIDE];   // partial transpose [q][d|l] 26624 B
};

__global__ __launch_bounds__(256) void attn_f16(const _Float16* __restrict__ qh,
                                                const _Float16* __restrict__ kh,
                                                const _Float16* __restrict__ vt,
                                                float* __restrict__ obp)
{
    __shared__ AttnSmem sm;
    const int tid = threadIdx.x;
    const int w = tid >> 6, lane = tid & 63, ln = lane & 31, h = lane >> 5;
    const int bh = blockIdx.x, qt = blockIdx.y, half = blockIdx.z;
    const int kt0 = half * 1024;

    // one-time: Vts rows 48..63 (48 = ones for l, rest zero) — slot-invariant
    for (int i = tid; i < 16 * 72; i += 256) {
        const int r = 48 + i / 72, c = i - (i / 72) * 72;
        sm.a.Vts[r][c] = (r == 48) ? (_Float16)1.0f : (_Float16)0.0f;
    }

    // Q B-frags (3, dh = 16i + 8h + 0..7), query = qt*128 + w*32 + ln
    f16x8 qf[3];
    {
        const _Float16* qp = qh + (size_t)(bh * 2048 + qt * 128 + w * 32 + ln) * 48 + 8 * h;
        qf[0] = *(const f16x8*)qp;
        qf[1] = *(const f16x8*)(qp + 16);
        qf[2] = *(const f16x8*)(qp + 32);
    }

    f32x16 o0, o1;
    #pragma unroll
    for (int r = 0; r < 16; r++) { o0[r] = 0.f; o1[r] = 0.f; }

    const _Float16* kbase = kh + (size_t)bh * 2048 * 48;
    const _Float16* vbase = vt + (size_t)bh * 48 * 2048;

    const int kr0 = tid / 6,         kc0 = (tid % 6) * 8;
    const int kid1 = tid + 256;
    const int kr1 = kid1 / 6,        kc1 = (kid1 % 6) * 8;
    const int vr0 = tid >> 3,        vc0 = (tid & 7) * 8;
    const int vr1 = (tid + 256) >> 3;
    const int vslot_lo = 16 * ((tid & 7) >> 1) + 4 * (tid & 1);
    const _Float16* ks0 = kbase + (size_t)kr0 * 48 + kc0;
    const _Float16* ks1 = kbase + (size_t)kr1 * 48 + kc1;
    const _Float16* vs0 = vbase + (size_t)vr0 * 2048 + vc0;
    const _Float16* vs1 = vbase + (size_t)vr1 * 2048 + vc0;

    f16x8 rk0 = *(const f16x8*)(ks0 + (size_t)kt0 * 48);
    f16x8 rv0 = *(const f16x8*)(vs0 + kt0);
    f16x8 rk1, rv1;
    if (tid < 128) {
        rk1 = *(const f16x8*)(ks1 + (size_t)kt0 * 48);
        rv1 = *(const f16x8*)(vs1 + kt0);
    }

    for (int kt = kt0; kt < kt0 + 1024; kt += 64) {
        __syncthreads();
        *(f16x8*)&sm.a.Ks[kr0][kc0] = rk0;
        {
            const f16x4* rvh = (const f16x4*)&rv0;
            *(f16x4*)&sm.a.Vts[vr0][vslot_lo]     = rvh[0];
            *(f16x4*)&sm.a.Vts[vr0][vslot_lo + 8] = rvh[1];
        }
        if (tid < 128) {
            *(f16x8*)&sm.a.Ks[kr1][kc1] = rk1;
            const f16x4* rvh = (const f16x4*)&rv1;
            *(f16x4*)&sm.a.Vts[vr1][vslot_lo]     = rvh[0];
            *(f16x4*)&sm.a.Vts[vr1][vslot_lo + 8] = rvh[1];
        }
        __syncthreads();
        if (kt + 64 < kt0 + 1024) {
            rk0 = *(const f16x8*)(ks0 + (size_t)(kt + 64) * 48);
            rv0 = *(const f16x8*)(vs0 + kt + 64);
            if (tid < 128) {
                rk1 = *(const f16x8*)(ks1 + (size_t)(kt + 64) * 48);
                rv1 = *(const f16x8*)(vs1 + kt + 64);
            }
        }

        // ---- S^T = K.Q^T ----
        f32x16 s0, s1;
        #pragma unroll
        for (int r = 0; r < 16; r++) { s0[r] = 0.f; s1[r] = 0.f; }
        #pragma unroll
        for (int i = 0; i < 3; i++) {
            const f16x8 ka0 = *(const f16x8*)&sm.a.Ks[ln][16 * i + 8 * h];
            s0 = __builtin_amdgcn_mfma_f32_32x32x16_f16(ka0, qf[i], s0, 0, 0, 0);
            const f16x8 ka1 = *(const f16x8*)&sm.a.Ks[32 + ln][16 * i + 8 * h];
            s1 = __builtin_amdgcn_mfma_f32_32x32x16_f16(ka1, qf[i], s1, 0, 0, 0);
        }

        // ---- P = exp2(S^T) packed directly as PV B-frags ----
        f16x8 pbf[4];
        #pragma unroll
        for (int j = 0; j < 8; j++) {
            pbf[0][j] = (_Float16)exp2f(s0[j]);
            pbf[1][j] = (_Float16)exp2f(s0[8 + j]);
            pbf[2][j] = (_Float16)exp2f(s1[j]);
            pbf[3][j] = (_Float16)exp2f(s1[8 + j]);
        }

        // ---- O^T += V^T.P^T ----
        #pragma unroll
        for (int c = 0; c < 4; c++) {
            const f16x8 av0 = *(const f16x8*)&sm.a.Vts[ln][16 * c + 8 * h];
            o0 = __builtin_amdgcn_mfma_f32_32x32x16_f16(av0, pbf[c], o0, 0, 0, 0);
            const f16x8 av1 = *(const f16x8*)&sm.a.Vts[32 + ln][16 * c + 8 * h];
            o1 = __builtin_amdgcn_mfma_f32_32x32x16_f16(av1, pbf[c], o1, 0, 0, 0);
        }
    }

    // ---- partial epilogue: transpose to [q][d] fp32, write raw + l ----
    __syncthreads();
    #pragma unroll
    for (int r = 0; r < 16; r++)
        sm.Otf[w * 32 + ln][(r & 3) + 8 * (r >> 2) + 4 * h] = o0[r];
    #pragma unroll
    for (int r = 0; r < 8; r++)
        sm.Otf[w * 32 + ln][32 + (r & 3) + 8 * (r >> 2) + 4 * h] = o1[r];
    if (h == 0) sm.Otf[w * 32 + ln][48] = o1[8];   // l (row 48 of O^T)
    __syncthreads();
    float* op = obp + half * OPHALF + (size_t)(bh * 16 + qt) * OPTILE;
    #pragma unroll
    for (int i = 0; i < 6; i++) {
        const int c = i * 256 + tid;               // 0..1535: row*12 chunks
        const int row = c / 12, cc = c % 12;
        *(float4*)&op[row * OPSTRIDE + cc * 4] = *(const float4*)&sm.Otf[row][cc * 4];
    }
    if (tid < 128) op[tid * OPSTRIDE + 48] = sm.Otf[tid][48];
}

// ---------------------------------------------------------------------------
// finalize: sum the two key-halves, normalize, emit f16 ab. Grid 512x256.
// ---------------------------------------------------------------------------
__global__ __launch_bounds__(256) void finalize(const float* __restrict__ obp,
                                                _Float16* __restrict__ ab)
{
    __shared__ float linv[128];
    const int tid = threadIdx.x;
    const int bid = blockIdx.x;
    const int bh = bid >> 4, qt = bid & 15;
    const float* p0 = obp + (size_t)(bh * 16 + qt) * OPTILE;
    const float* p1 = p0 + OPHALF;
    if (tid < 128)
        linv[tid] = 1.f / (p0[tid * OPSTRIDE + 48] + p1[tid * OPSTRIDE + 48]);
    __syncthreads();
    const int b = bh >> 3, hd = bh & 7;
    #pragma unroll
    for (int i = 0; i < 6; i++) {
        const int c = i * 256 + tid;               // 0..1535
        const int row = c / 12, cc = c % 12;
        const float4 a = *(const float4*)&p0[row * OPSTRIDE + cc * 4];
        const float4 bb = *(const float4*)&p1[row * OPSTRIDE + cc * 4];
        const float inv = linv[row];
        f16x4 hv;
        hv[0] = (_Float16)((a.x + bb.x) * inv);
        hv[1] = (_Float16)((a.y + bb.y) * inv);
        hv[2] = (_Float16)((a.z + bb.z) * inv);
        hv[3] = (_Float16)((a.w + bb.w) * inv);
        const int q = qt * 128 + row;
        *(f16x4*)&ab[(size_t)(b * 2048 + q) * 384 + hd * 48 + cc * 4] = hv;
    }
}

// ---------------------------------------------------------------------------
// Proj GEMM: A = ab[8192][384] f16, Bt = wprojt[384][384] f16, +bias -> fp32
// ---------------------------------------------------------------------------
__global__ __launch_bounds__(256) void proj_f16(const _Float16* __restrict__ A,
                                                const _Float16* __restrict__ Bt,
                                                const float* __restrict__ bias,
                                                float* __restrict__ out)
{
    __shared__ _Float16 As[64][72];
    __shared__ _Float16 Bs[64][72];
    const int tid = threadIdx.x;
    const int w = tid >> 6, lane = tid & 63, cl = lane & 15, quad = lane >> 4;
    const int bm = blockIdx.x, bn = blockIdx.y;

    f32x4 acc[4];
    const f32x4 z4 = {0.f, 0.f, 0.f, 0.f};
    #pragma unroll
    for (int t = 0; t < 4; t++) acc[t] = z4;

    const int ar = tid >> 3, ac = (tid & 7) * 8;
    const _Float16* Ag = A  + (size_t)(bm * 64 + ar) * 384 + ac;
    const _Float16* Bg = Bt + (size_t)(bn * 64 + ar) * 384 + ac;

    f16x8 pa[2], pb[2];
    #pragma unroll
    for (int j = 0; j < 2; j++) {
        pa[j] = *(const f16x8*)(Ag + (size_t)(32 * j) * 384);
        pb[j] = *(const f16x8*)(Bg + (size_t)(32 * j) * 384);
    }

    for (int k0 = 0; k0 < 384; k0 += 64) {
        __syncthreads();
        #pragma unroll
        for (int j = 0; j < 2; j++) {
            *(f16x8*)&As[ar + 32 * j][ac] = pa[j];
            *(f16x8*)&Bs[ar + 32 * j][ac] = pb[j];
        }
        __syncthreads();
        if (k0 + 64 < 384) {
            #pragma unroll
            for (int j = 0; j < 2; j++) {
                pa[j] = *(const f16x8*)(Ag + (size_t)(32 * j) * 384 + k0 + 64);
                pb[j] = *(const f16x8*)(Bg + (size_t)(32 * j) * 384 + k0 + 64);
            }
        }
        #pragma unroll
        for (int kh2 = 0; kh2 < 2; kh2++) {
            const f16x8 af = *(const f16x8*)&As[w * 16 + cl][kh2 * 32 + quad * 8];
            #pragma unroll
            for (int t = 0; t < 4; t++) {
                const f16x8 bf = *(const f16x8*)&Bs[t * 16 + cl][kh2 * 32 + quad * 8];
                acc[t] = __builtin_amdgcn_mfma_f32_16x16x32_f16(af, bf, acc[t], 0, 0, 0);
            }
        }
    }

    #pragma unroll
    for (int t = 0; t < 4; t++) {
        const int col = bn * 64 + t * 16 + cl;
        const float bv = bias[col];
        #pragma unroll
        for (int r = 0; r < 4; r++) {
            const int row = bm * 64 + w * 16 + quad * 4 + r;
            out[(size_t)row * 384 + col] = acc[t][r] + bv;
        }
    }
}

// ---------------------------------------------------------------------------
extern "C" void kernel_launch(void* const* d_in, const int* in_sizes, int n_in,
                              void* d_out, int out_size, void* d_ws, size_t ws_size,
                              hipStream_t stream) {
    const float* x     = (const float*)d_in[0];  // [4,2048,384]
    const float* Wqkv  = (const float*)d_in[1];  // [384,1152]
    const float* Wproj = (const float*)d_in[2];  // [384,384]
    const float* bproj = (const float*)d_in[3];  // [384]
    float* out = (float*)d_out;

    char* ws = (char*)d_ws;
    _Float16* xh     = (_Float16*)(ws + 0);          // 6,291,456
    _Float16* wqkvt  = (_Float16*)(ws + 6291456);    //   884,736
    _Float16* wprojt = (_Float16*)(ws + 7176192);    //   294,912
    _Float16* qh     = (_Float16*)(ws + 7471104);    // 6,291,456
    _Float16* kh     = (_Float16*)(ws + 13762560);   // 6,291,456
    _Float16* vt     = (_Float16*)(ws + 20054016);   // 6,291,456
    _Float16* ab     = (_Float16*)(ws + 26345472);   // 6,291,456
    float*    obp    = (float*)(ws + 32636928);      // 2*512*128*52*4 = 27,262,976
    // total 59,899,904 B

    prep<<<400, 256, 0, stream>>>((const float4*)x, Wqkv, Wproj,
                                  (f16x4*)xh, wqkvt, wprojt);
    qkv_f16<<<dim3(64, 9), 256, 0, stream>>>(xh, wqkvt, qh, kh, vt);
    attn_f16<<<dim3(32, 16, 2), 256, 0, stream>>>(qh, kh, vt, obp);
    finalize<<<512, 256, 0, stream>>>(obp, ab);
    proj_f16<<<dim3(128, 6), 256, 0, stream>>>(ab, wprojt, bproj, out);
}